// Round 5
// baseline (503.740 us; speedup 1.0000x reference)
//
#include <hip/hip_runtime.h>
#include <math.h>

#define NN 13824            // D*H*W
#define SNODE 884736        // NN*64
#define NTILE 432           // NN/32 node tiles
#define GRIDB 512
#define INVC (1.0f / 55296.0f)

// ---------------- device-scope grid barrier (all GRIDB blocks co-resident) ----
// LDS 60KB -> exactly 2 blocks/CU by LDS; 4 waves/CU needs no VGPR cap, so all
// 512 blocks are resident: spin barrier is safe. __threadfence emits the
// agent-scope L2 wb/inv required for cross-XCD visibility (same as grid.sync).
__device__ __forceinline__ void gbar(unsigned* cnt, unsigned target) {
    __syncthreads();
    if (threadIdx.x == 0) {
        __threadfence();
        atomicAdd(cnt, 1u);
        while (__hip_atomic_load(cnt, __ATOMIC_RELAXED, __HIP_MEMORY_SCOPE_AGENT) < target)
            __builtin_amdgcn_s_sleep(2);
        __threadfence();
    }
    __syncthreads();
}

// ---------------- LDS layout (floats), 15040 total = 60160 B -----------------
// [0     .. 2303]  hs[c*36+nl]      : 64ch x 32node h tile (lives whole kernel)
// [2304  ..14847]  wsm[c*196+d]     : weights^T (proj phases)   -- time-shared:
//                  crossL[c*36+nl]  : 2304..4607 (combine/apply)
//                  ysL[nl*68+d]     : 4608..6783 (combine)
//                  red[64]          : 6784..6847 (combine)
//                  attn: per-wave buf[24*196] + P[24*28] at 2304 + wv*5376
// [14848..15039]   bias192 (staged once in P0, survives all phases)

__device__ __forceinline__ void stage_weights(
    const float* __restrict__ tw, const float* __restrict__ pw,
    const float* __restrict__ gw, float* wsm, int tid)
{
    #pragma unroll 4
    for (int it = 0; it < 24; it++) {
        int idx = it * 512 + tid * 4;
        int d = idx >> 6, c4 = idx & 63;
        const float* src = (d < 64) ? tw : (d < 128) ? pw : gw;
        int dd = d & 63;
        float4 w4 = *(const float4*)&src[dd * 64 + c4];
        float a[4] = {w4.x, w4.y, w4.z, w4.w};
        #pragma unroll
        for (int j = 0; j < 4; j++) {              // j-rotation: 16-way -> 4-way
            int jj = (j + tid) & 3;
            wsm[(c4 + jj) * 196 + d] = a[jj];
        }
    }
}

__device__ __forceinline__ void proj_compute(
    const float* hs, const float* wsm, const float* bias192,
    float* __restrict__ tpg, int n0, int tid)
{
    const int dgrp = tid & 15, ngrp = tid >> 4;
    const int d0 = dgrp * 12, nl0 = ngrp * 4;
    float acc[4][12];
    #pragma unroll
    for (int q = 0; q < 4; q++)
        #pragma unroll
        for (int j = 0; j < 12; j++) acc[q][j] = 0.f;

    #pragma unroll 2
    for (int c = 0; c < 64; c++) {
        float4 hv = *(const float4*)&hs[c * 36 + nl0];
        float w[12];
        *(float4*)&w[0] = *(const float4*)&wsm[c * 196 + d0];
        *(float4*)&w[4] = *(const float4*)&wsm[c * 196 + d0 + 4];
        *(float4*)&w[8] = *(const float4*)&wsm[c * 196 + d0 + 8];
        #pragma unroll
        for (int j = 0; j < 12; j++) {
            acc[0][j] += hv.x * w[j];
            acc[1][j] += hv.y * w[j];
            acc[2][j] += hv.z * w[j];
            acc[3][j] += hv.w * w[j];
        }
    }
    float b[12];
    *(float4*)&b[0] = *(const float4*)&bias192[d0];
    *(float4*)&b[4] = *(const float4*)&bias192[d0 + 4];
    *(float4*)&b[8] = *(const float4*)&bias192[d0 + 8];
    #pragma unroll
    for (int q = 0; q < 4; q++) {
        float* o = tpg + (size_t)(n0 + nl0 + q) * 192 + d0;
        #pragma unroll
        for (int k = 0; k < 3; k++) {
            float4 v;
            v.x = acc[q][4*k]   + b[4*k];
            v.y = acc[q][4*k+1] + b[4*k+1];
            v.z = acc[q][4*k+2] + b[4*k+2];
            v.w = acc[q][4*k+3] + b[4*k+3];
            *(float4*)&o[4*k] = v;
        }
    }
}

// one wave handles one 24-node line; wave-private LDS, no block barriers.
__device__ __forceinline__ void attn_line(
    const float* __restrict__ tpg, float* __restrict__ ypart,
    float* __restrict__ lpart, float* buf, float* P, int line, int lane)
{
    const int axis = line / 576, L = line % 576;
    int base, stride;
    if (axis == 0)      { base = L * 24;                    stride = 1;   }
    else if (axis == 1) { base = (L / 24) * 576 + (L % 24); stride = 24;  }
    else                { base = L;                         stride = 576; }
    const bool excl = (axis != 2);

    __threadfence_block();   // WAR vs previous pass's reads of buf
    // stage 24 rows x 192 (theta|phi|g contiguous in tpg)
    #pragma unroll 3
    for (int q = 0; q < 18; q++) {
        int idx = q * 64 + lane;
        int row = idx / 48, ch = (idx % 48) * 4;
        *(float4*)&buf[row * 196 + ch] =
            *(const float4*)&tpg[(size_t)(base + row * stride) * 192 + ch];
    }
    __threadfence_block();   // staging visible to cross-lane reads (same wave)

    // S = theta @ phi^T, 3x3 per lane on an 8x8 lane grid; P = exp(S)
    // (no max-subtract: logits O(10), fp32-safe; softmax shift-invariant)
    const int li = lane >> 3, lj = lane & 7;
    const int r0 = li * 3, c0 = lj * 3;
    float sa[3][3];
    #pragma unroll
    for (int a = 0; a < 3; a++)
        #pragma unroll
        for (int b = 0; b < 3; b++) sa[a][b] = 0.f;
    #pragma unroll 4
    for (int d4 = 0; d4 < 64; d4 += 4) {
        float4 t[3], p[3];
        #pragma unroll
        for (int a = 0; a < 3; a++) t[a] = *(const float4*)&buf[(r0 + a) * 196 + d4];
        #pragma unroll
        for (int b = 0; b < 3; b++) p[b] = *(const float4*)&buf[(c0 + b) * 196 + 64 + d4];
        #pragma unroll
        for (int a = 0; a < 3; a++)
            #pragma unroll
            for (int b = 0; b < 3; b++)
                sa[a][b] += t[a].x * p[b].x + t[a].y * p[b].y +
                            t[a].z * p[b].z + t[a].w * p[b].w;
    }
    float rs[3] = {0.f, 0.f, 0.f};
    #pragma unroll
    for (int a = 0; a < 3; a++)
        #pragma unroll
        for (int b = 0; b < 3; b++) {
            float e = (excl && (r0 + a) == (c0 + b)) ? 0.f : __expf(sa[a][b]);
            rs[a] += e;
            P[(r0 + a) * 28 + c0 + b] = e;
        }
    // row sums: reduce over lj (lane bits 0..2)
    #pragma unroll
    for (int off = 1; off <= 4; off <<= 1)
        #pragma unroll
        for (int a = 0; a < 3; a++) rs[a] += __shfl_xor(rs[a], off);
    if (lj == 0) {
        #pragma unroll
        for (int a = 0; a < 3; a++)
            lpart[(size_t)axis * NN + base + (r0 + a) * stride] = rs[a];
    }
    __threadfence_block();   // P visible to cross-lane reads

    // Y = P @ g : lane = (rowgroup rg of 6, d-quad dg)
    const int rg = lane >> 4, dg = lane & 15;
    float acc[6][4];
    #pragma unroll
    for (int i = 0; i < 6; i++)
        #pragma unroll
        for (int k = 0; k < 4; k++) acc[i][k] = 0.f;
    #pragma unroll 4
    for (int c = 0; c < 24; c++) {
        float4 gv = *(const float4*)&buf[c * 196 + 128 + dg * 4];
        #pragma unroll
        for (int i = 0; i < 6; i++) {
            float p = P[(rg * 6 + i) * 28 + c];
            acc[i][0] += p * gv.x; acc[i][1] += p * gv.y;
            acc[i][2] += p * gv.z; acc[i][3] += p * gv.w;
        }
    }
    float* yp = ypart + (size_t)axis * SNODE;
    #pragma unroll
    for (int i = 0; i < 6; i++) {
        float4 v = {acc[i][0], acc[i][1], acc[i][2], acc[i][3]};
        *(float4*)&yp[(size_t)(base + (rg * 6 + i) * stride) * 64 + dg * 4] = v;
    }
}

__device__ __forceinline__ void combine_phase(
    const float* __restrict__ ypart, const float* __restrict__ lpart,
    const float* __restrict__ r_w, const float* __restrict__ r_b,
    float* ysL, float* crossL, float* red, float* gsum, int n0, int tid)
{
    const int wv = tid >> 6, lane = tid & 63;
    // merge 3 axis partials, normalize -> ysL
    #pragma unroll
    for (int i = 0; i < 4; i++) {
        int idx = i * 512 + tid * 4;
        int nl = idx >> 6, d4 = idx & 63;
        int n = n0 + nl;
        float lv = lpart[n] + lpart[NN + n] + lpart[2 * NN + n];
        float4 a = *(const float4*)&ypart[(size_t)n * 64 + d4];
        float4 b = *(const float4*)&ypart[SNODE + (size_t)n * 64 + d4];
        float4 c = *(const float4*)&ypart[2 * SNODE + (size_t)n * 64 + d4];
        float inv = 1.f / lv;
        float4 v = {(a.x + b.x + c.x) * inv, (a.y + b.y + c.y) * inv,
                    (a.z + b.z + c.z) * inv, (a.w + b.w + c.w) * inv};
        *(float4*)&ysL[nl * 68 + d4] = v;
    }
    __syncthreads();
    // cross = ys @ r_w^T + r_b ; 4 nodes (strided) x 4 channels per thread
    const int cg = tid & 15, g = tid >> 4;    // channels 4cg..+3 = GN group cg
    float acc[4][4];
    #pragma unroll
    for (int m = 0; m < 4; m++)
        #pragma unroll
        for (int j = 0; j < 4; j++) acc[m][j] = 0.f;
    #pragma unroll 2
    for (int dd = 0; dd < 64; dd += 4) {
        float4 rw[4], ys[4];
        #pragma unroll
        for (int j = 0; j < 4; j++) rw[j] = *(const float4*)&r_w[(cg * 4 + j) * 64 + dd];
        #pragma unroll
        for (int m = 0; m < 4; m++) ys[m] = *(const float4*)&ysL[(g + 8 * m) * 68 + dd];
        #pragma unroll
        for (int m = 0; m < 4; m++)
            #pragma unroll
            for (int j = 0; j < 4; j++)
                acc[m][j] += ys[m].x * rw[j].x + ys[m].y * rw[j].y +
                             ys[m].z * rw[j].z + ys[m].w * rw[j].w;
    }
    float s = 0.f, ss = 0.f;
    #pragma unroll
    for (int m = 0; m < 4; m++)
        #pragma unroll
        for (int j = 0; j < 4; j++) {
            float v = acc[m][j] + r_b[cg * 4 + j];
            crossL[(cg * 4 + j) * 36 + g + 8 * m] = v;
            s += v; ss += v * v;
        }
    s  += __shfl_xor(s, 16);  s  += __shfl_xor(s, 32);
    ss += __shfl_xor(ss, 16); ss += __shfl_xor(ss, 32);
    if (lane < 16) { red[wv * 32 + lane] = s; red[wv * 32 + 16 + lane] = ss; }
    __syncthreads();
    if (tid < 16) {
        atomicAdd(&gsum[tid * 16],       red[tid] + red[32 + tid]);        // 64B-spread
        atomicAdd(&gsum[512 + tid * 16], red[16 + tid] + red[48 + tid]);
    }
}

__global__ void __launch_bounds__(128) zero_kernel(float* g, unsigned* cnt) {
    int t = blockIdx.x * 128 + threadIdx.x;   // grid 16 -> 2048
    g[t] = 0.f;
    if (t == 0) *cnt = 0u;
}

__global__ void __launch_bounds__(128) mega_kernel(
    const float* __restrict__ x,
    const float* __restrict__ theta_w, const float* __restrict__ theta_b,
    const float* __restrict__ phi_w,   const float* __restrict__ phi_b,
    const float* __restrict__ g_w,     const float* __restrict__ g_b,
    const float* __restrict__ r_w,     const float* __restrict__ r_b,
    const float* __restrict__ gn_g,    const float* __restrict__ gn_b,
    const float* __restrict__ bn_g,    const float* __restrict__ bn_b,
    const float* __restrict__ bn_m,    const float* __restrict__ bn_v,
    float* __restrict__ tpg, float* __restrict__ ypart, float* __restrict__ lpart,
    float* __restrict__ gsumA, float* __restrict__ gsumB,
    unsigned* __restrict__ cnt, float* __restrict__ out)
{
    __shared__ float lds[15040];
    float* hs      = lds;
    float* wsm     = lds + 2304;
    float* crossL  = lds + 2304;
    float* ysL     = lds + 4608;
    float* red     = lds + 6784;
    float* bias192 = lds + 14848;

    const int tid = threadIdx.x;
    const int blk = blockIdx.x;
    const int wv = tid >> 6, lane = tid & 63;
    const int n0 = blk * 32;
    float* abuf = lds + 2304 + wv * 5376;   // attn per-wave buffer
    float* aP   = abuf + 4704;

    // ---- P0: stage x -> hs, weights, bias; project -> tpg
    if (blk < NTILE) {
        int c0 = tid >> 3, q4 = (tid & 7) * 4;
        #pragma unroll
        for (int cc = 0; cc < 64; cc += 16)
            *(float4*)&hs[(c0 + cc) * 36 + q4] =
                *(const float4*)&x[(size_t)(c0 + cc) * NN + n0 + q4];
        stage_weights(theta_w, phi_w, g_w, wsm, tid);
        if (tid < 64) {
            bias192[tid] = theta_b[tid];
            bias192[64 + tid] = phi_b[tid];
            bias192[128 + tid] = g_b[tid];
        }
        __syncthreads();
        proj_compute(hs, wsm, bias192, tpg, n0, tid);
    }
    gbar(cnt, 1 * GRIDB);

    // ---- P1: line attention, 1728 lines over 1024 wave-slots
    for (int pass = 0; pass < 2; pass++) {
        int line = pass * 1024 + blk * 2 + wv;
        if (line < 1728) attn_line(tpg, ypart, lpart, abuf, aP, line, lane);
    }
    gbar(cnt, 2 * GRIDB);

    // ---- P2: combine -> crossL (LDS) + GN stats
    if (blk < NTILE) combine_phase(ypart, lpart, r_w, r_b, ysL, crossL, red, gsumA, n0, tid);
    gbar(cnt, 3 * GRIDB);

    // ---- P3: h = x + GN(cross) in LDS (no global round-trip); P4: project
    if (blk < NTILE) {
        #pragma unroll
        for (int i = 0; i < 4; i++) {
            int idx = i * 512 + tid * 4;
            int c = idx >> 5, nlo = idx & 31;
            int gr = c >> 2;
            float mean = gsumA[gr * 16] * INVC;
            float var  = gsumA[512 + gr * 16] * INVC - mean * mean;
            float sc = rsqrtf(var + 1e-5f) * gn_g[c];
            float sh = gn_b[c] - mean * sc;
            float4 cr = *(const float4*)&crossL[c * 36 + nlo];
            float4 h  = *(const float4*)&hs[c * 36 + nlo];
            h.x += cr.x * sc + sh; h.y += cr.y * sc + sh;
            h.z += cr.z * sc + sh; h.w += cr.w * sc + sh;
            *(float4*)&hs[c * 36 + nlo] = h;
        }
        __syncthreads();               // crossL reads done before wsm overwrite
        stage_weights(theta_w, phi_w, g_w, wsm, tid);
        __syncthreads();
        proj_compute(hs, wsm, bias192, tpg, n0, tid);
    }
    gbar(cnt, 4 * GRIDB);

    // ---- P5: line attention (iter 1)
    for (int pass = 0; pass < 2; pass++) {
        int line = pass * 1024 + blk * 2 + wv;
        if (line < 1728) attn_line(tpg, ypart, lpart, abuf, aP, line, lane);
    }
    gbar(cnt, 5 * GRIDB);

    // ---- P6: combine (iter 1)
    if (blk < NTILE) combine_phase(ypart, lpart, r_w, r_b, ysL, crossL, red, gsumB, n0, tid);
    gbar(cnt, 6 * GRIDB);

    // ---- P7: out = relu(BN(h + GN(cross)))   (h tile still live in LDS)
    if (blk < NTILE) {
        #pragma unroll
        for (int i = 0; i < 4; i++) {
            int idx = i * 512 + tid * 4;
            int c = idx >> 5, nlo = idx & 31;
            int gr = c >> 2;
            float mean = gsumB[gr * 16] * INVC;
            float var  = gsumB[512 + gr * 16] * INVC - mean * mean;
            float sc = rsqrtf(var + 1e-5f) * gn_g[64 + c];
            float sh = gn_b[64 + c] - mean * sc;
            float bsc = rsqrtf(bn_v[c] + 1e-5f) * bn_g[c];
            float bsh = bn_b[c] - bn_m[c] * bsc;
            float4 cr = *(const float4*)&crossL[c * 36 + nlo];
            float4 h  = *(const float4*)&hs[c * 36 + nlo];
            float4 o;
            o.x = fmaxf((h.x + cr.x * sc + sh) * bsc + bsh, 0.f);
            o.y = fmaxf((h.y + cr.y * sc + sh) * bsc + bsh, 0.f);
            o.z = fmaxf((h.z + cr.z * sc + sh) * bsc + bsh, 0.f);
            o.w = fmaxf((h.w + cr.w * sc + sh) * bsc + bsh, 0.f);
            *(float4*)&out[(size_t)c * NN + n0 + nlo] = o;
        }
    }
}

extern "C" void kernel_launch(void* const* d_in, const int* in_sizes, int n_in,
                              void* d_out, int out_size, void* d_ws, size_t ws_size,
                              hipStream_t stream)
{
    const float* x        = (const float*)d_in[0];
    // d_in[1] = nbr_idx: unused — neighbor structure is separable (3 axis lines)
    const float* phi_w    = (const float*)d_in[2];
    const float* phi_b    = (const float*)d_in[3];
    const float* theta_w  = (const float*)d_in[4];
    const float* theta_b  = (const float*)d_in[5];
    const float* G_w      = (const float*)d_in[6];
    const float* G_b      = (const float*)d_in[7];
    const float* r_w      = (const float*)d_in[8];
    const float* r_b      = (const float*)d_in[9];
    const float* gn_gamma = (const float*)d_in[10];
    const float* gn_beta  = (const float*)d_in[11];
    const float* bn_gamma = (const float*)d_in[12];
    const float* bn_beta  = (const float*)d_in[13];
    const float* bn_mean  = (const float*)d_in[14];
    const float* bn_var   = (const float*)d_in[15];

    float* ws = (float*)d_ws;
    float* tpg   = ws;                       // (N,192) theta|phi|g
    float* ypart = ws + 2654208;             // 3 x (N,64) per-axis partials
    float* lpart = ws + 5308416;             // 3 x (N)
    float* gsumA = ws + 5349888;             // GN stats iter0 (1024, 64B-spread)
    float* gsumB = ws + 5350912;             // GN stats iter1
    unsigned* cnt = (unsigned*)(ws + 5351936);

    zero_kernel<<<16, 128, 0, stream>>>(gsumA, cnt);   // zeroes gsumA+gsumB+cnt
    mega_kernel<<<GRIDB, 128, 0, stream>>>(
        x, theta_w, theta_b, phi_w, phi_b, G_w, G_b, r_w, r_b,
        gn_gamma, gn_beta, bn_gamma, bn_beta, bn_mean, bn_var,
        tpg, ypart, lpart, gsumA, gsumB, cnt, (float*)d_out);
}

// Round 6
// 233.001 us; speedup vs baseline: 2.1620x; 2.1620x over previous
//
#include <hip/hip_runtime.h>
#include <math.h>

#define NN 13824   // D*H*W
#define LW 24      // line width

// ---------------- fused GN-apply + residual + projection ----------------
// grid = 216 tiles x 3 tensors. Each block computes ONE tensor (theta/phi/g)
// for a 64-node tile: out = hs @ W^T + b, written into tpg (N,192).
// mode 0: hs = x tile. mode 1: hs = x + GN(cross); ts==0 block stores h_out.
__global__ __launch_bounds__(256) void apply_proj_kernel(
    const float* __restrict__ x,
    const float* __restrict__ cross, const float* __restrict__ gsum,
    const float* __restrict__ gn_g, const float* __restrict__ gn_b,
    float* __restrict__ h_out, int mode,
    const float* __restrict__ theta_w, const float* __restrict__ theta_b,
    const float* __restrict__ phi_w, const float* __restrict__ phi_b,
    const float* __restrict__ g_w, const float* __restrict__ g_b,
    float* __restrict__ tpg)
{
    __shared__ float hs[64 * 64];   // hs[c*64 + nl]
    __shared__ float ws[64 * 68];   // scratch (cross^T) then weights^T [c*68 + d]

    const int tid = threadIdx.x;
    const int tile = blockIdx.x / 3, ts = blockIdx.x % 3;
    const int n0 = tile * 64;

    const float* wsel = (ts == 0) ? theta_w : (ts == 1) ? phi_w : g_w;
    const float* bsel = (ts == 0) ? theta_b : (ts == 1) ? phi_b : g_b;

    if (mode == 0) {
        for (int i = tid; i < 4096; i += 256) {
            int c = i >> 6, nl = i & 63;
            hs[c * 64 + nl] = x[(size_t)c * NN + n0 + nl];
        }
    } else {
        for (int i = tid; i < 4096; i += 256) {       // cross^T into scratch
            int nl = i >> 6, c = i & 63;
            ws[c * 68 + nl] = cross[(size_t)(n0 + nl) * 64 + c];
        }
        __syncthreads();
        const float inv_cnt = 1.f / 55296.f;
        for (int i = tid; i < 4096; i += 256) {
            int c = i >> 6, nl = i & 63;
            int gr = c >> 2;
            float mean = gsum[gr * 16] * inv_cnt;
            float var = gsum[512 + gr * 16] * inv_cnt - mean * mean;
            float v = (ws[c * 68 + nl] - mean) * rsqrtf(var + 1e-5f) * gn_g[c] + gn_b[c];
            size_t o = (size_t)c * NN + n0 + nl;
            float hv = x[o] + v;
            hs[c * 64 + nl] = hv;
            if (ts == 0) h_out[o] = hv;               // one block writes residual
        }
        __syncthreads();
    }

    // stage this tensor's weights transposed: ws[c*68 + d] = W[d][c]
    for (int i = tid; i < 4096; i += 256) {
        int d = i >> 6, c = i & 63;
        ws[c * 68 + d] = wsel[d * 64 + c];
    }
    __syncthreads();

    // 4 nodes x 4 dims per thread; lanes consecutive in d for coalesced stores
    const int d0  = (tid & 15) * 4;
    const int nl0 = (tid >> 4) * 4;
    float acc[4][4];
    #pragma unroll
    for (int q = 0; q < 4; q++)
        #pragma unroll
        for (int j = 0; j < 4; j++) acc[q][j] = 0.f;

    #pragma unroll 4
    for (int c = 0; c < 64; c++) {
        float4 hv = *(const float4*)&hs[c * 64 + nl0];
        float4 wv = *(const float4*)&ws[c * 68 + d0];
        #pragma unroll
        for (int j = 0; j < 4; j++) {
            float w = (&wv.x)[j];
            acc[0][j] += hv.x * w;
            acc[1][j] += hv.y * w;
            acc[2][j] += hv.z * w;
            acc[3][j] += hv.w * w;
        }
    }
    float4 bias = *(const float4*)&bsel[d0];
    #pragma unroll
    for (int q = 0; q < 4; q++) {
        float4 v;
        v.x = acc[q][0] + bias.x; v.y = acc[q][1] + bias.y;
        v.z = acc[q][2] + bias.z; v.w = acc[q][3] + bias.w;
        *(float4*)&tpg[(size_t)(n0 + nl0 + q) * 192 + ts * 64 + d0] = v;
    }
}

// ---------------- dense line attention: one WAVE per line ----------------
// block = 256 threads = 4 waves = 4 lines; grid = 432 covers 1728 lines.
// theta/phi are NOT staged in LDS: the S-phase reads them straight from
// global with 8-way intra-wave address sharing (128B/instr, zero
// amplification). g is prefetched to registers at kernel start and parked
// in LDS only for the Y-phase. LDS/wave = 9.2KB -> 4 blocks/CU, 16 waves/CU.
// No max-subtract: logits O(10), fp32 exp safe; softmax shift-invariant,
// so per-axis partials (exp-sums, exp-weighted sums) merge by addition.
__global__ __launch_bounds__(256, 4) void line_attn_kernel(
    const float* __restrict__ tpg,   // (N,192) theta|phi|g
    float* __restrict__ y_part,      // 3 buffers of (N,64)
    float* __restrict__ l_part,      // 3 buffers of (N)
    float* __restrict__ gsum)        // zeroed here for combine's atomics
{
    __shared__ float wbuf[4][2304];  // per wave: g[24*68] @0, P[24*28] @1632

    const int tid = threadIdx.x;
    const int wv = tid >> 6, lane = tid & 63;
    const int line = blockIdx.x * 4 + wv;
    const int axis = line / 576, L = line % 576;
    float* gb = wbuf[wv];
    float* P  = wbuf[wv] + 1632;

    if (blockIdx.x == 0) {
        for (int i = tid; i < 1024; i += 256) gsum[i] = 0.f;
    }

    int base, stride;
    if (axis == 0)      { base = L * 24;                    stride = 1;   }
    else if (axis == 1) { base = (L / 24) * 576 + (L % 24); stride = 24;  }
    else                { base = L;                         stride = 576; }
    const bool excl = (axis != 2);

    // prefetch g rows into registers (coalesced: 4 rows x 256B per instr)
    float4 gpre[6];
    const int grow = lane >> 4, gquad = lane & 15;
    #pragma unroll
    for (int q = 0; q < 6; q++) {
        int row = q * 4 + grow;
        gpre[q] = *(const float4*)&tpg[(size_t)(base + row * stride) * 192 + 128 + gquad * 4];
    }

    // S = theta @ phi^T, 3x3 per lane on an 8x8 lane grid, operands from global
    const int li = lane >> 3, lj = lane & 7;
    const int r0 = li * 3, c0 = lj * 3;
    const float* trow[3];
    const float* prow[3];
    #pragma unroll
    for (int a = 0; a < 3; a++) {
        trow[a] = tpg + (size_t)(base + (r0 + a) * stride) * 192;
        prow[a] = tpg + (size_t)(base + (c0 + a) * stride) * 192 + 64;
    }
    float sa[3][3];
    #pragma unroll
    for (int a = 0; a < 3; a++)
        #pragma unroll
        for (int b = 0; b < 3; b++) sa[a][b] = 0.f;
    #pragma unroll 4
    for (int d4 = 0; d4 < 64; d4 += 4) {
        float4 t[3], p[3];
        #pragma unroll
        for (int a = 0; a < 3; a++) t[a] = *(const float4*)&trow[a][d4];
        #pragma unroll
        for (int b = 0; b < 3; b++) p[b] = *(const float4*)&prow[b][d4];
        #pragma unroll
        for (int a = 0; a < 3; a++)
            #pragma unroll
            for (int b = 0; b < 3; b++)
                sa[a][b] += t[a].x * p[b].x + t[a].y * p[b].y +
                            t[a].z * p[b].z + t[a].w * p[b].w;
    }

    // P = exp(S) (self-masked for W/H axes) + row sums
    float rs[3] = {0.f, 0.f, 0.f};
    #pragma unroll
    for (int a = 0; a < 3; a++)
        #pragma unroll
        for (int b = 0; b < 3; b++) {
            float e = (excl && (r0 + a) == (c0 + b)) ? 0.f : __expf(sa[a][b]);
            rs[a] += e;
            P[(r0 + a) * 28 + c0 + b] = e;
        }
    #pragma unroll
    for (int off = 1; off <= 4; off <<= 1)
        #pragma unroll
        for (int a = 0; a < 3; a++) rs[a] += __shfl_xor(rs[a], off);
    if (lj == 0) {
        #pragma unroll
        for (int a = 0; a < 3; a++)
            l_part[(size_t)axis * NN + base + (r0 + a) * stride] = rs[a];
    }

    // park g in LDS for the Y-phase's per-column broadcast reads
    #pragma unroll
    for (int q = 0; q < 6; q++)
        *(float4*)&gb[(q * 4 + grow) * 68 + gquad * 4] = gpre[q];
    __threadfence_block();   // P + g visible to cross-lane reads (same wave)

    // Y = P @ g : lane = (rowgroup rg of 6 rows, d-quad dg)
    const int rg = lane >> 4, dg = lane & 15;
    float acc[6][4];
    #pragma unroll
    for (int i = 0; i < 6; i++)
        #pragma unroll
        for (int k = 0; k < 4; k++) acc[i][k] = 0.f;
    #pragma unroll 4
    for (int c = 0; c < 24; c++) {
        float4 gv = *(const float4*)&gb[c * 68 + dg * 4];
        #pragma unroll
        for (int i = 0; i < 6; i++) {
            float p = P[(rg * 6 + i) * 28 + c];
            acc[i][0] += p * gv.x; acc[i][1] += p * gv.y;
            acc[i][2] += p * gv.z; acc[i][3] += p * gv.w;
        }
    }
    float* yp = y_part + (size_t)axis * NN * 64;
    #pragma unroll
    for (int i = 0; i < 6; i++) {
        float4 v = {acc[i][0], acc[i][1], acc[i][2], acc[i][3]};
        *(float4*)&yp[(size_t)(base + (rg * 6 + i) * stride) * 64 + dg * 4] = v;
    }
}

// ---------------- combine: merge axes, normalize, project r_w, GN partials ----------------
__global__ __launch_bounds__(256) void combine_kernel(
    const float* __restrict__ y_part, const float* __restrict__ l_part,
    const float* __restrict__ r_w, const float* __restrict__ r_b,
    float* __restrict__ cross, float* __restrict__ gsum)
{
    __shared__ float ys[16 * 68];
    __shared__ float red_s[4][64], red_ss[4][64];

    const int tid = threadIdx.x;
    const int d = tid & 63, w = tid >> 6;
    const int n0 = blockIdx.x * 16;
    const size_t S = (size_t)NN * 64;

    #pragma unroll
    for (int q = 0; q < 4; q++) {
        int nn = w * 4 + q;
        int n = n0 + nn;
        float lv = l_part[n] + l_part[NN + n] + l_part[2 * NN + n];
        size_t o = (size_t)n * 64 + d;
        float yv = y_part[o] + y_part[S + o] + y_part[2 * S + o];
        ys[nn * 68 + d] = yv / lv;
    }
    __syncthreads();

    const int c = d;
    float rb = r_b[c];
    float acc[4] = {rb, rb, rb, rb};
    for (int dd = 0; dd < 64; dd += 4) {
        float4 r4 = *(const float4*)&r_w[c * 64 + dd];
        #pragma unroll
        for (int q = 0; q < 4; q++) {
            float4 y4 = *(const float4*)&ys[(w * 4 + q) * 68 + dd];
            acc[q] += r4.x * y4.x + r4.y * y4.y + r4.z * y4.z + r4.w * y4.w;
        }
    }
    float s = 0.f, ss = 0.f;
    #pragma unroll
    for (int q = 0; q < 4; q++) {
        int n = n0 + w * 4 + q;
        cross[(size_t)n * 64 + c] = acc[q];
        s += acc[q];
        ss += acc[q] * acc[q];
    }
    red_s[w][c] = s;
    red_ss[w][c] = ss;
    __syncthreads();
    if (w == 0) {
        float ts  = red_s[0][c] + red_s[1][c] + red_s[2][c] + red_s[3][c];
        float tss = red_ss[0][c] + red_ss[1][c] + red_ss[2][c] + red_ss[3][c];
        ts  += __shfl_xor(ts, 1);  ts  += __shfl_xor(ts, 2);
        tss += __shfl_xor(tss, 1); tss += __shfl_xor(tss, 2);
        if ((c & 3) == 0) {
            atomicAdd(&gsum[(c >> 2) * 16], ts);          // 64B-strided: no contention
            atomicAdd(&gsum[512 + (c >> 2) * 16], tss);
        }
    }
}

// ---------------- final: h2 = h1 + GN(cross); out = relu(BN(h2)) ----------------
__global__ __launch_bounds__(256) void final_kernel(
    const float* __restrict__ cross,
    const float* __restrict__ gsum,
    const float* __restrict__ gn_g, const float* __restrict__ gn_b,
    const float* __restrict__ h_in,
    const float* __restrict__ bn_g, const float* __restrict__ bn_b,
    const float* __restrict__ bn_m, const float* __restrict__ bn_v,
    float* __restrict__ out)
{
    __shared__ float t[64 * 65];
    const int tid = threadIdx.x;
    const int n0 = blockIdx.x * 64;
    for (int i = tid; i < 4096; i += 256) {
        int nl = i >> 6, c = i & 63;
        t[c * 65 + nl] = cross[(size_t)(n0 + nl) * 64 + c];
    }
    __syncthreads();
    const float inv_cnt = 1.f / 55296.f;
    for (int i = tid; i < 4096; i += 256) {
        int c = i >> 6, nl = i & 63;
        int gr = c >> 2;
        float mean = gsum[gr * 16] * inv_cnt;
        float var = gsum[512 + gr * 16] * inv_cnt - mean * mean;
        float v = (t[c * 65 + nl] - mean) * rsqrtf(var + 1e-5f) * gn_g[c] + gn_b[c];
        size_t o = (size_t)c * NN + n0 + nl;
        float h2 = h_in[o] + v;
        float bnv = (h2 - bn_m[c]) * rsqrtf(bn_v[c] + 1e-5f) * bn_g[c] + bn_b[c];
        out[o] = fmaxf(bnv, 0.f);
    }
}

extern "C" void kernel_launch(void* const* d_in, const int* in_sizes, int n_in,
                              void* d_out, int out_size, void* d_ws, size_t ws_size,
                              hipStream_t stream)
{
    const float* x        = (const float*)d_in[0];
    // d_in[1] = nbr_idx: unused — neighbor structure is separable (3 axis lines)
    const float* phi_w    = (const float*)d_in[2];
    const float* phi_b    = (const float*)d_in[3];
    const float* theta_w  = (const float*)d_in[4];
    const float* theta_b  = (const float*)d_in[5];
    const float* G_w      = (const float*)d_in[6];
    const float* G_b      = (const float*)d_in[7];
    const float* r_w      = (const float*)d_in[8];
    const float* r_b      = (const float*)d_in[9];
    const float* gn_gamma = (const float*)d_in[10];
    const float* gn_beta  = (const float*)d_in[11];
    const float* bn_gamma = (const float*)d_in[12];
    const float* bn_beta  = (const float*)d_in[13];
    const float* bn_mean  = (const float*)d_in[14];
    const float* bn_var   = (const float*)d_in[15];

    float* ws = (float*)d_ws;
    const size_t S = (size_t)NN * 64;
    float* h1    = ws;             // (64,N) after iter-0 update
    float* tpg   = ws + S;         // (N,192) theta|phi|g
    float* ypart = ws + 4 * S;     // 3 x (N,64) per-axis partials
    float* cross = ws + 7 * S;     // (N,64)
    float* lpart = ws + 8 * S;     // 3 x (N)
    float* gsum  = ws + 8 * S + 3 * NN;  // GN accumulators (1024 floats)

    // iter 0
    apply_proj_kernel<<<648, 256, 0, stream>>>(x, cross, gsum, gn_gamma, gn_beta,
                                               h1, 0,
                                               theta_w, theta_b, phi_w, phi_b,
                                               G_w, G_b, tpg);
    line_attn_kernel<<<432, 256, 0, stream>>>(tpg, ypart, lpart, gsum);
    combine_kernel<<<864, 256, 0, stream>>>(ypart, lpart, r_w, r_b, cross, gsum);
    // iter 1 (proj reads gsum before attn re-zeroes it: stream order)
    apply_proj_kernel<<<648, 256, 0, stream>>>(x, cross, gsum, gn_gamma, gn_beta,
                                               h1, 1,
                                               theta_w, theta_b, phi_w, phi_b,
                                               G_w, G_b, tpg);
    line_attn_kernel<<<432, 256, 0, stream>>>(tpg, ypart, lpart, gsum);
    combine_kernel<<<864, 256, 0, stream>>>(ypart, lpart, r_w, r_b, cross, gsum);
    // epilogue
    final_kernel<<<216, 256, 0, stream>>>(cross, gsum, gn_gamma + 64, gn_beta + 64,
                                          h1, bn_gamma, bn_beta, bn_mean, bn_var,
                                          (float*)d_out);
}